// Round 14
// baseline (315.702 us; speedup 1.0000x reference)
//
#include <hip/hip_runtime.h>
#include <hip/hip_bf16.h>

// out = X + s*(relu(A_hat @ (X @ W_agg)) - X), s = sigmoid(wg)*sigmoid(wl)
// X[8192,256] f32, A_hat[8192,8192] f32, W[256,256] f32. Out f32 [8192,256].
// Round 14: r9 gemm (best, verified) + FUSED finalize. Per-mtile completion
// counters (zeroed by prep each launch -> graph-replay-safe); the 8th kseg
// block to finish a mtile sums the 8 bf16 P slices and applies the X/s
// epilogue, overlapping the reduction with other blocks' GEMM work. Removes
// the serial finalize8 pass (~48MB traffic) + one launch boundary.

typedef __attribute__((ext_vector_type(4))) float f32x4;
typedef __attribute__((ext_vector_type(8))) __bf16 bf16x8;
typedef __attribute__((ext_vector_type(8))) unsigned short u16x8;

#define GLOBAL_AS __attribute__((address_space(1)))
#define LDS_AS __attribute__((address_space(3)))

static __device__ __forceinline__ void gload16(const void* g, void* l) {
  __builtin_amdgcn_global_load_lds((const GLOBAL_AS void*)g, (LDS_AS void*)l, 16, 0, 0);
}
static __device__ __forceinline__ void gload16_stream(const void* g, void* l) {
  __builtin_amdgcn_global_load_lds((const GLOBAL_AS void*)g, (LDS_AS void*)l, 16, 0, 0x12);
}

static __device__ __forceinline__ unsigned short f2bf_bits(float f) {
  __bf16 h = (__bf16)f;
  return __builtin_bit_cast(unsigned short, h);
}
static __device__ __forceinline__ float bf2f(unsigned short u) {
  return __builtin_bit_cast(float, (unsigned)u << 16);
}

// ---------------- prep: s vector + W^T + counter reset -----------------------------
__global__ void prep_kernel(const float* __restrict__ W,
                            const float* __restrict__ wg,
                            const float* __restrict__ wl,
                            unsigned short* __restrict__ WT,  // [8][256][32] bf16
                            float* __restrict__ s,
                            int* __restrict__ counters) {     // [64] per-mtile
  int tid = blockIdx.x * 256 + threadIdx.x;  // 0..65535
  int k = tid >> 8, n = tid & 255;
  float w = W[tid];  // W[k][n]
  int kt = k >> 5, kloc = k & 31;
  WT[kt * 8192 + n * 32 + kloc] = f2bf_bits(w);
  if (tid < 8192) {
    float sg = 1.0f / (1.0f + expf(-wg[0]));
    float sl = 1.0f / (1.0f + expf(-wl[tid]));
    s[tid] = sg * sl;
  }
  if (tid < 64) counters[tid] = 0;  // runs before gemm_ks8 every launch/replay
}

// ---------------- gemm0: XW = X @ W  ->  XWT2 in MFMA B-frag layout ----------------
// XWT2 block for (c=k/64, wp=n/32, kk=(k>>5)&1, ni=(n>>4)&1): 64 lanes x 16B, lane
// = (n&15) + 16*((k>>3)&3), holding 8 consecutive bf16 along k.
__global__ __launch_bounds__(256, 2) void gemm_xw(
    const float* __restrict__ X,              // [8192][256]
    const unsigned short* __restrict__ WT,    // tiled [8][256][32]
    unsigned short* __restrict__ XWT2) {      // 4 MiB, frag-layout
  __shared__ float As[2][32 * 32];
  __shared__ unsigned short Bs[2][128 * 32];

  const int bm = blockIdx.x & 255;
  const int bn = blockIdx.x >> 8;
  const int m0 = bm * 32;
  const int tid = threadIdx.x;
  const int w = tid >> 6;
  const int l = tid & 63;
  const int lr = l & 15;
  const int lq = l >> 4;

  const int pA = w * 1024 + l * 16;
  const int rA = pA >> 7;
  const int qA = (pA >> 4) & 7;
  const int ssA = qA ^ (rA & 7);
  const char* Asrc0 = (const char*)X + (size_t)(m0 + rA) * 1024 + ssA * 16;
  const char* Bsrc0 = (const char*)WT + bn * 8192 + w * 2048 + l * 16;

  f32x4 acc[2][2];
#pragma unroll
  for (int i = 0; i < 2; ++i)
#pragma unroll
    for (int j = 0; j < 2; ++j) acc[i][j] = (f32x4){0.f, 0.f, 0.f, 0.f};

  auto stage = [&](int t, int buf) {
    gload16(Asrc0 + (size_t)t * 128, (char*)&As[buf][0] + w * 1024);
    const char* bs = Bsrc0 + (size_t)t * 16384;
    gload16(bs, (char*)&Bs[buf][0] + w * 2048);
    gload16(bs + 1024, (char*)&Bs[buf][0] + w * 2048 + 1024);
  };

  auto compute = [&](int buf) {
    bf16x8 af[2];
#pragma unroll
    for (int mi = 0; mi < 2; ++mi) {
      int r = mi * 16 + lr;
      const float* ap = &As[buf][r * 32];
      int s0 = (2 * lq) ^ (r & 7);
      int s1 = (2 * lq + 1) ^ (r & 7);
      f32x4 a0 = *(const f32x4*)(ap + s0 * 4);
      f32x4 a1 = *(const f32x4*)(ap + s1 * 4);
      bf16x8 v;
      v[0] = (__bf16)a0.x; v[1] = (__bf16)a0.y; v[2] = (__bf16)a0.z; v[3] = (__bf16)a0.w;
      v[4] = (__bf16)a1.x; v[5] = (__bf16)a1.y; v[6] = (__bf16)a1.z; v[7] = (__bf16)a1.w;
      af[mi] = v;
    }
    bf16x8 bfr[2];
#pragma unroll
    for (int ni = 0; ni < 2; ++ni) {
      int row = w * 32 + ni * 16 + lr;
      bfr[ni] = *(const bf16x8*)(&Bs[buf][row * 32 + lq * 8]);
    }
#pragma unroll
    for (int mi = 0; mi < 2; ++mi)
#pragma unroll
      for (int ni = 0; ni < 2; ++ni)
        acc[mi][ni] = __builtin_amdgcn_mfma_f32_16x16x32_bf16(af[mi], bfr[ni], acc[mi][ni], 0, 0, 0);
  };

  stage(0, 0);
  __syncthreads();
  for (int t = 0; t < 8; ++t) {
    int cur = t & 1;
    if (t + 1 < 8) stage(t + 1, cur ^ 1);
    compute(cur);
    __syncthreads();
  }

  // epilogue -> XWT2 frag layout. k (main-GEMM contraction) = bm*32 + mi*16 + lq*4
#pragma unroll
  for (int mi = 0; mi < 2; ++mi)
#pragma unroll
    for (int ni2 = 0; ni2 < 2; ++ni2) {
      f32x4 z = acc[mi][ni2];
      int n = bn * 128 + w * 32 + ni2 * 16 + lr;
      int k = bm * 32 + mi * 16 + lq * 4;
      int c = k >> 6;
      int kk = (k >> 5) & 1;
      int ni = (n >> 4) & 1;
      int wp = n >> 5;
      int lane2 = (n & 15) + 16 * ((k >> 3) & 3);
      int j0 = k & 7;  // 0 or 4
      size_t off = (((size_t)c * 8 + wp) * 4 + kk * 2 + ni) * 512 + lane2 * 8 + j0;
      ushort4 u;
      u.x = f2bf_bits(z[0]); u.y = f2bf_bits(z[1]);
      u.z = f2bf_bits(z[2]); u.w = f2bf_bits(z[3]);
      *(ushort4*)(XWT2 + off) = u;
    }
}

// ---------------- gemm_ks8: P[kseg] = A[:, kseg] @ XW[kseg] + fused finalize -------
// Main loop IDENTICAL to round 9 (verified best). Epilogue: write bf16 P slice,
// fence+count; the 8th finisher of each mtile sums all 8 slices for its 128
// rows and applies out = x + s*(relu(sum)-x), overlapped with other blocks.
__global__ __launch_bounds__(512, 4) void gemm_ks8(
    const float* __restrict__ A,              // [8192][8192]
    const unsigned short* __restrict__ B2,    // XWT2 frag layout
    unsigned short* __restrict__ P,           // [8][8192][256] bf16 partials
    const float* __restrict__ X,              // [8192][256]
    const float* __restrict__ s,              // [8192]
    float* __restrict__ out,                  // [8192][256]
    int* __restrict__ counters) {             // [64]
  __shared__ unsigned short Al[2][8 * 512];   // 2 x 8KB: [mi][fl][8bf16]
  __shared__ int lastFlag;

  const int bid = blockIdx.x;
  const int mtile = bid >> 3, kseg = bid & 7;  // kseg == XCD id (round-robin)
  const int m0 = mtile * 128;
  const int tid = threadIdx.x;  // 0..511
  const int w = tid >> 6, l = tid & 63;
  const int lr = l & 15, lq = l >> 4;

  // staging: thread t -> A row r=t>>2, k-chunk c4=t&3 (8 consecutive floats).
  const int r = tid >> 2, c4 = tid & 3;
  const float* gA = A + (size_t)(m0 + r) * 8192 + kseg * 1024 + c4 * 8;
  const int woff = (r >> 4) * 512 + ((r & 15) + 16 * c4) * 8;  // ushort index

  const unsigned short* Bbase = B2 + (size_t)kseg * 262144 + l * 8;

  f32x4 acc[8][2];
#pragma unroll
  for (int i = 0; i < 8; ++i)
#pragma unroll
    for (int j = 0; j < 2; ++j) acc[i][j] = (f32x4){0.f, 0.f, 0.f, 0.f};

  f32x4 sa0, sa1;  // staged A regs
  bf16x8 Bf0, Bf1;

  auto loadA = [&](int h) {
    sa0 = *(const f32x4*)(gA + h * 32);
    sa1 = *(const f32x4*)(gA + h * 32 + 4);
  };
  auto writeA = [&](int h) {  // cvt + ds_write A(h) -> Al[h&1]
    bf16x8 b;
    b[0] = (__bf16)sa0.x; b[1] = (__bf16)sa0.y; b[2] = (__bf16)sa0.z; b[3] = (__bf16)sa0.w;
    b[4] = (__bf16)sa1.x; b[5] = (__bf16)sa1.y; b[6] = (__bf16)sa1.z; b[7] = (__bf16)sa1.w;
    *(bf16x8*)(&Al[h & 1][woff]) = b;
  };
  auto loadB = [&](int h) {  // iter h: c=h>>1, kk=h&1; wave w = wp
    const unsigned short* p = Bbase + ((((h >> 1) * 8 + w) * 4 + (h & 1) * 2) << 9);
    Bf0 = *(const bf16x8*)(p);
    Bf1 = *(const bf16x8*)(p + 512);
  };
  auto compute = [&](int h) {
    const unsigned short* Ab = &Al[h & 1][0];
#pragma unroll
    for (int mi = 0; mi < 8; ++mi) {
      bf16x8 af = *(const bf16x8*)(Ab + mi * 512 + l * 8);  // lane-linear
      acc[mi][0] = __builtin_amdgcn_mfma_f32_16x16x32_bf16(af, Bf0, acc[mi][0], 0, 0, 0);
      acc[mi][1] = __builtin_amdgcn_mfma_f32_16x16x32_bf16(af, Bf1, acc[mi][1], 0, 0, 0);
    }
  };

  // prologue: A(0) staged+written, B(0)+A(1) in flight
  loadA(0);
  writeA(0);
  loadB(0);
  loadA(1);
  asm volatile("s_waitcnt lgkmcnt(0)" ::: "memory");
  asm volatile("s_barrier" ::: "memory");

  for (int h = 0; h < 31; ++h) {
    compute(h);
    loadB(h + 1);
    writeA(h + 1);
    if (h < 30) loadA(h + 2);
    asm volatile("s_waitcnt lgkmcnt(0)" ::: "memory");
    asm volatile("s_barrier" ::: "memory");
  }
  compute(31);

  // ---- write bf16 partial P[kseg][m][n] ----
  unsigned short* Pb = P + (size_t)kseg * (8192 * 256);
#pragma unroll
  for (int mi = 0; mi < 8; ++mi)
#pragma unroll
    for (int ni = 0; ni < 2; ++ni) {
      f32x4 z = acc[mi][ni];
      int n = w * 32 + ni * 16 + lr;
#pragma unroll
      for (int i = 0; i < 4; ++i) {
        int m = m0 + mi * 16 + lq * 4 + i;
        Pb[(size_t)m * 256 + n] = f2bf_bits(z[i]);
      }
    }

  // ---- completion protocol (device-scope; cross-XCD per G16) ----
  __threadfence();     // make this block's P stores visible device-wide
  __syncthreads();     // all threads' stores+fences precede the atomic
  if (tid == 0) {
    int done = atomicAdd(&counters[mtile], 1);
    lastFlag = (done == 7);
  }
  __syncthreads();
  if (!lastFlag) return;

  // ---- winner: fused finalize for rows m0..m0+127 ----
  __threadfence();  // acquire: see all 8 slices' P stores
  for (int g = tid; g < 4096; g += 512) {  // 128 rows x 32 groups of 8 cols
    int mloc = g >> 5;
    int nd = (g & 31) * 8;
    int m = m0 + mloc;
    float accf[8] = {0.f, 0.f, 0.f, 0.f, 0.f, 0.f, 0.f, 0.f};
#pragma unroll
    for (int ks = 0; ks < 8; ++ks) {
      u16x8 v = *(const u16x8*)(P + (size_t)ks * 2097152 + (size_t)m * 256 + nd);
#pragma unroll
      for (int j = 0; j < 8; ++j) accf[j] += bf2f(v[j]);
    }
    float sv = s[m];
    f32x4 x0 = *(const f32x4*)(X + (size_t)m * 256 + nd);
    f32x4 x1 = *(const f32x4*)(X + (size_t)m * 256 + nd + 4);
    f32x4 o0, o1;
#pragma unroll
    for (int j = 0; j < 4; ++j) {
      o0[j] = x0[j] + sv * (fmaxf(accf[j], 0.f) - x0[j]);
      o1[j] = x1[j] + sv * (fmaxf(accf[4 + j], 0.f) - x1[j]);
    }
    *(f32x4*)(out + (size_t)m * 256 + nd) = o0;
    *(f32x4*)(out + (size_t)m * 256 + nd + 4) = o1;
  }
}

// ================= fallback path (round-6 kernels, unchanged) ======================
template <int NT, bool SPLIT>
__global__ __launch_bounds__(512, 4) void gemm_main(
    const float* __restrict__ A,
    const unsigned short* __restrict__ B2,
    const float* __restrict__ X,
    const float* __restrict__ s,
    float* __restrict__ out,
    float* __restrict__ P) {
  __shared__ float As[4][32 * 64];

  const int bid = blockIdx.x;
  const int m0 = SPLIT ? (bid >> 1) * 32 : bid * 32;
  const int khalf = SPLIT ? (bid & 1) : 0;
  const int tid = threadIdx.x;
  const int w = tid >> 6;
  const int l = tid & 63;
  const int lr = l & 15;
  const int lq = l >> 4;

  const int rA = tid >> 4;
  const int qA = tid & 15;
  const int sqA = qA ^ (rA & 15);
  const char* Asrc =
      (const char*)A + (size_t)(m0 + rA) * 32768 + (size_t)khalf * 16384 + sqA * 16;
  const char* Bbase =
      (const char*)B2 + (size_t)khalf * 64 * 32768 + (size_t)w * 4096 + (size_t)l * 16;

  f32x4 acc[2][2];
#pragma unroll
  for (int i = 0; i < 2; ++i)
#pragma unroll
    for (int j = 0; j < 2; ++j) acc[i][j] = (f32x4){0.f, 0.f, 0.f, 0.f};

  struct BF { bf16x8 a, b, c, d; };
  BF Bf0, Bf1;

  auto stageA = [&](int h, int buf) {
    gload16_stream(Asrc + (size_t)h * 256, (char*)&As[buf][0] + w * 1024);
  };
  auto loadB = [&](int h, BF& f) {
    const char* p = Bbase + (size_t)h * 32768;
    f.a = *(const bf16x8*)(p);
    f.b = *(const bf16x8*)(p + 1024);
    f.c = *(const bf16x8*)(p + 2048);
    f.d = *(const bf16x8*)(p + 3072);
  };

  auto compute = [&](int buf, const BF& f) {
    const char* Ab = (const char*)&As[buf][0];
    bf16x8 af[2][2];
#pragma unroll
    for (int kk = 0; kk < 2; ++kk)
#pragma unroll
      for (int mi = 0; mi < 2; ++mi) {
        int rr = mi * 16 + lr;
        int s0 = (kk * 8 + 2 * lq) ^ (rr & 15);
        int s1 = ((kk * 8 + 2 * lq) + 1) ^ (rr & 15);
        f32x4 a0 = *(const f32x4*)(Ab + rr * 256 + s0 * 16);
        f32x4 a1 = *(const f32x4*)(Ab + rr * 256 + s1 * 16);
        bf16x8 v;
        v[0] = (__bf16)a0.x; v[1] = (__bf16)a0.y; v[2] = (__bf16)a0.z; v[3] = (__bf16)a0.w;
        v[4] = (__bf16)a1.x; v[5] = (__bf16)a1.y; v[6] = (__bf16)a1.z; v[7] = (__bf16)a1.w;
        af[kk][mi] = v;
      }
    acc[0][0] = __builtin_amdgcn_mfma_f32_16x16x32_bf16(af[0][0], f.a, acc[0][0], 0, 0, 0);
    acc[0][1] = __builtin_amdgcn_mfma_f32_16x16x32_bf16(af[0][0], f.b, acc[0][1], 0, 0, 0);
    acc[1][0] = __builtin_amdgcn_mfma_f32_16x16x32_bf16(af[0][1], f.a, acc[1][0], 0, 0, 0);
    acc[1][1] = __builtin_amdgcn_mfma_f32_16x16x32_bf16(af[0][1], f.b, acc[1][1], 0, 0, 0);
    acc[0][0] = __builtin_amdgcn_mfma_f32_16x16x32_bf16(af[1][0], f.c, acc[0][0], 0, 0, 0);
    acc[0][1] = __builtin_amdgcn_mfma_f32_16x16x32_bf16(af[1][0], f.d, acc[0][1], 0, 0, 0);
    acc[1][0] = __builtin_amdgcn_mfma_f32_16x16x32_bf16(af[1][1], f.c, acc[1][0], 0, 0, 0);
    acc[1][1] = __builtin_amdgcn_mfma_f32_16x16x32_bf16(af[1][1], f.d, acc[1][1], 0, 0, 0);
  };

  stageA(0, 0);
  loadB(0, Bf0);
  stageA(1, 1);
  loadB(1, Bf1);
  stageA(2, 2);
  stageA(3, 3);

  for (int h = 0; h < NT - 4; h += 2) {
    asm volatile("s_waitcnt vmcnt(6)" ::: "memory");
    asm volatile("s_barrier" ::: "memory");
    compute(h & 3, Bf0);
    asm volatile("s_waitcnt lgkmcnt(0)" ::: "memory");
    asm volatile("s_barrier" ::: "memory");
    loadB(h + 2, Bf0);
    stageA(h + 4, h & 3);

    asm volatile("s_waitcnt vmcnt(6)" ::: "memory");
    asm volatile("s_barrier" ::: "memory");
    compute((h + 1) & 3, Bf1);
    asm volatile("s_waitcnt lgkmcnt(0)" ::: "memory");
    asm volatile("s_barrier" ::: "memory");
    loadB(h + 3, Bf1);
    stageA(h + 5, (h + 1) & 3);
  }
  asm volatile("s_waitcnt vmcnt(6)" ::: "memory");
  asm volatile("s_barrier" ::: "memory");
  compute(0, Bf0);
  asm volatile("s_waitcnt lgkmcnt(0)" ::: "memory");
  asm volatile("s_barrier" ::: "memory");
  loadB(NT - 2, Bf0);

  asm volatile("s_waitcnt vmcnt(5)" ::: "memory");
  asm volatile("s_barrier" ::: "memory");
  compute(1, Bf1);
  asm volatile("s_waitcnt lgkmcnt(0)" ::: "memory");
  asm volatile("s_barrier" ::: "memory");
  loadB(NT - 1, Bf1);

  asm volatile("s_waitcnt vmcnt(4)" ::: "memory");
  asm volatile("s_barrier" ::: "memory");
  compute(2, Bf0);
  asm volatile("s_waitcnt lgkmcnt(0)" ::: "memory");
  asm volatile("s_barrier" ::: "memory");

  asm volatile("s_waitcnt vmcnt(0)" ::: "memory");
  asm volatile("s_barrier" ::: "memory");
  compute(3, Bf1);

  if (SPLIT) {
    float* Pb = P + (size_t)khalf * 8192 * 256;
#pragma unroll
    for (int mi = 0; mi < 2; ++mi)
#pragma unroll
      for (int ni = 0; ni < 2; ++ni) {
        f32x4 z = acc[mi][ni];
        int n = w * 32 + ni * 16 + lr;
#pragma unroll
        for (int i = 0; i < 4; ++i) {
          int m = m0 + mi * 16 + lq * 4 + i;
          Pb[m * 256 + n] = z[i];
        }
      }
  } else {
#pragma unroll
    for (int mi = 0; mi < 2; ++mi)
#pragma unroll
      for (int ni = 0; ni < 2; ++ni) {
        f32x4 z = acc[mi][ni];
        int n = w * 32 + ni * 16 + lr;
#pragma unroll
        for (int i = 0; i < 4; ++i) {
          int m = m0 + mi * 16 + lq * 4 + i;
          float x = X[m * 256 + n];
          float sv = s[m];
          out[m * 256 + n] = x + sv * (fmaxf(z[i], 0.f) - x);
        }
      }
  }
}

__global__ __launch_bounds__(256) void finalize_kernel(
    const float* __restrict__ P,
    const float* __restrict__ X,
    const float* __restrict__ s,
    float* __restrict__ out) {
  int i = blockIdx.x * 256 + threadIdx.x;
  int m = i >> 6;
  f32x4 p0 = *(const f32x4*)(P + (size_t)i * 4);
  f32x4 p1 = *(const f32x4*)(P + 2097152 + (size_t)i * 4);
  f32x4 x = *(const f32x4*)(X + (size_t)i * 4);
  float sv = s[m];
  f32x4 o;
#pragma unroll
  for (int j = 0; j < 4; ++j) o[j] = x[j] + sv * (fmaxf(p0[j] + p1[j], 0.f) - x[j]);
  *(f32x4*)(out + (size_t)i * 4) = o;
}

extern "C" void kernel_launch(void* const* d_in, const int* in_sizes, int n_in,
                              void* d_out, int out_size, void* d_ws, size_t ws_size,
                              hipStream_t stream) {
  const float* X = (const float*)d_in[0];
  const float* A = (const float*)d_in[1];
  const float* wg = (const float*)d_in[2];
  const float* wl = (const float*)d_in[3];
  const float* W = (const float*)d_in[4];
  float* out = (float*)d_out;

  // ws: XWT2 4 MiB | WT 128 KiB | s 32 KiB | P bf16 32 MiB | counters 256 B
  unsigned short* XWT2 = (unsigned short*)d_ws;
  unsigned short* WT = (unsigned short*)((char*)d_ws + 4194304);
  float* s = (float*)((char*)d_ws + 4194304 + 131072);
  char* Pbase = (char*)d_ws + 4194304 + 131072 + 32768;
  int* counters = (int*)(Pbase + (size_t)8 * 8192 * 256 * 2);

  const size_t head = 4194304 + 131072 + 32768;
  const size_t need8 = head + (size_t)8 * 8192 * 256 * 2 + 256;  // P + counters
  const size_t need2 = head + (size_t)2 * 8192 * 256 * 4;        // f32 partials

  prep_kernel<<<256, 256, 0, stream>>>(W, wg, wl, WT, s, counters);
  gemm_xw<<<512, 256, 0, stream>>>(X, WT, XWT2);

  if (ws_size >= need8) {
    gemm_ks8<<<512, 512, 0, stream>>>(A, XWT2, (unsigned short*)Pbase, X, s, out,
                                      counters);
  } else if (ws_size >= need2) {
    gemm_main<64, true><<<512, 512, 0, stream>>>(A, XWT2, X, s, out, (float*)Pbase);
    finalize_kernel<<<2048, 256, 0, stream>>>((const float*)Pbase, X, s, out);
  } else {
    gemm_main<128, false><<<256, 512, 0, stream>>>(A, XWT2, X, s, out, nullptr);
  }
}

// Round 15
// 103.046 us; speedup vs baseline: 3.0637x; 3.0637x over previous
//
#include <hip/hip_runtime.h>
#include <hip/hip_bf16.h>

// out = X + s*(relu(A_hat @ (X @ W_agg)) - X), s = sigmoid(wg)*sigmoid(wl)
// X[8192,256] f32, A_hat[8192,8192] f32, W[256,256] f32. Out f32 [8192,256].
// Round 15: EXACT revert to the round-9 kernel (verified best, 103.4us,
// absmax 7.8e-3). r10-r14 structural variants (BK=64 periods, s_sleep stagger,
// 2-deep E/O pipeline, producer/consumer waves, fused finalize w/ fences) all
// regressed or tied; r14's fence-based fusion deoptimized the main loop
// (VGPR 88->60, 4x slowdown). This decomposition's remaining ~2.4x gap vs the
// 43us A-read floor is the per-CU vmem/LDS/MFMA phase convoy, which HIP-level
// scheduling cannot break (guide: barrier-drain / compiler-waitcnt limitation).

typedef __attribute__((ext_vector_type(4))) float f32x4;
typedef __attribute__((ext_vector_type(8))) __bf16 bf16x8;
typedef __attribute__((ext_vector_type(8))) unsigned short u16x8;

#define GLOBAL_AS __attribute__((address_space(1)))
#define LDS_AS __attribute__((address_space(3)))

static __device__ __forceinline__ void gload16(const void* g, void* l) {
  __builtin_amdgcn_global_load_lds((const GLOBAL_AS void*)g, (LDS_AS void*)l, 16, 0, 0);
}
static __device__ __forceinline__ void gload16_stream(const void* g, void* l) {
  __builtin_amdgcn_global_load_lds((const GLOBAL_AS void*)g, (LDS_AS void*)l, 16, 0, 0x12);
}

static __device__ __forceinline__ unsigned short f2bf_bits(float f) {
  __bf16 h = (__bf16)f;
  return __builtin_bit_cast(unsigned short, h);
}
static __device__ __forceinline__ float bf2f(unsigned short u) {
  return __builtin_bit_cast(float, (unsigned)u << 16);
}

// ---------------- prep: s vector + W^T (bf16, tiled [k/32][n=256][32]) -------------
__global__ void prep_kernel(const float* __restrict__ W,
                            const float* __restrict__ wg,
                            const float* __restrict__ wl,
                            unsigned short* __restrict__ WT,  // [8][256][32] bf16
                            float* __restrict__ s) {
  int tid = blockIdx.x * 256 + threadIdx.x;  // 0..65535
  int k = tid >> 8, n = tid & 255;
  float w = W[tid];  // W[k][n]
  int kt = k >> 5, kloc = k & 31;
  WT[kt * 8192 + n * 32 + kloc] = f2bf_bits(w);
  if (tid < 8192) {
    float sg = 1.0f / (1.0f + expf(-wg[0]));
    float sl = 1.0f / (1.0f + expf(-wl[tid]));
    s[tid] = sg * sl;
  }
}

// ---------------- gemm0: XW = X @ W  ->  XWT2 in MFMA B-frag layout ----------------
// XWT2 block for (c=k/64, wp=n/32, kk=(k>>5)&1, ni=(n>>4)&1): 64 lanes x 16B, lane
// = (n&15) + 16*((k>>3)&3), holding 8 consecutive bf16 along k.
__global__ __launch_bounds__(256, 2) void gemm_xw(
    const float* __restrict__ X,              // [8192][256]
    const unsigned short* __restrict__ WT,    // tiled [8][256][32]
    unsigned short* __restrict__ XWT2) {      // 4 MiB, frag-layout
  __shared__ float As[2][32 * 32];
  __shared__ unsigned short Bs[2][128 * 32];

  const int bm = blockIdx.x & 255;
  const int bn = blockIdx.x >> 8;
  const int m0 = bm * 32;
  const int tid = threadIdx.x;
  const int w = tid >> 6;
  const int l = tid & 63;
  const int lr = l & 15;
  const int lq = l >> 4;

  const int pA = w * 1024 + l * 16;
  const int rA = pA >> 7;
  const int qA = (pA >> 4) & 7;
  const int ssA = qA ^ (rA & 7);
  const char* Asrc0 = (const char*)X + (size_t)(m0 + rA) * 1024 + ssA * 16;
  const char* Bsrc0 = (const char*)WT + bn * 8192 + w * 2048 + l * 16;

  f32x4 acc[2][2];
#pragma unroll
  for (int i = 0; i < 2; ++i)
#pragma unroll
    for (int j = 0; j < 2; ++j) acc[i][j] = (f32x4){0.f, 0.f, 0.f, 0.f};

  auto stage = [&](int t, int buf) {
    gload16(Asrc0 + (size_t)t * 128, (char*)&As[buf][0] + w * 1024);
    const char* bs = Bsrc0 + (size_t)t * 16384;
    gload16(bs, (char*)&Bs[buf][0] + w * 2048);
    gload16(bs + 1024, (char*)&Bs[buf][0] + w * 2048 + 1024);
  };

  auto compute = [&](int buf) {
    bf16x8 af[2];
#pragma unroll
    for (int mi = 0; mi < 2; ++mi) {
      int r = mi * 16 + lr;
      const float* ap = &As[buf][r * 32];
      int s0 = (2 * lq) ^ (r & 7);
      int s1 = (2 * lq + 1) ^ (r & 7);
      f32x4 a0 = *(const f32x4*)(ap + s0 * 4);
      f32x4 a1 = *(const f32x4*)(ap + s1 * 4);
      bf16x8 v;
      v[0] = (__bf16)a0.x; v[1] = (__bf16)a0.y; v[2] = (__bf16)a0.z; v[3] = (__bf16)a0.w;
      v[4] = (__bf16)a1.x; v[5] = (__bf16)a1.y; v[6] = (__bf16)a1.z; v[7] = (__bf16)a1.w;
      af[mi] = v;
    }
    bf16x8 bfr[2];
#pragma unroll
    for (int ni = 0; ni < 2; ++ni) {
      int row = w * 32 + ni * 16 + lr;
      bfr[ni] = *(const bf16x8*)(&Bs[buf][row * 32 + lq * 8]);
    }
#pragma unroll
    for (int mi = 0; mi < 2; ++mi)
#pragma unroll
      for (int ni = 0; ni < 2; ++ni)
        acc[mi][ni] = __builtin_amdgcn_mfma_f32_16x16x32_bf16(af[mi], bfr[ni], acc[mi][ni], 0, 0, 0);
  };

  stage(0, 0);
  __syncthreads();
  for (int t = 0; t < 8; ++t) {
    int cur = t & 1;
    if (t + 1 < 8) stage(t + 1, cur ^ 1);
    compute(cur);
    __syncthreads();
  }

  // epilogue -> XWT2 frag layout. k (main-GEMM contraction) = bm*32 + mi*16 + lq*4
#pragma unroll
  for (int mi = 0; mi < 2; ++mi)
#pragma unroll
    for (int ni2 = 0; ni2 < 2; ++ni2) {
      f32x4 z = acc[mi][ni2];
      int n = bn * 128 + w * 32 + ni2 * 16 + lr;
      int k = bm * 32 + mi * 16 + lq * 4;
      int c = k >> 6;
      int kk = (k >> 5) & 1;
      int ni = (n >> 4) & 1;
      int wp = n >> 5;
      int lane2 = (n & 15) + 16 * ((k >> 3) & 3);
      int j0 = k & 7;  // 0 or 4
      size_t off = (((size_t)c * 8 + wp) * 4 + kk * 2 + ni) * 512 + lane2 * 8 + j0;
      ushort4 u;
      u.x = f2bf_bits(z[0]); u.y = f2bf_bits(z[1]);
      u.z = f2bf_bits(z[2]); u.w = f2bf_bits(z[3]);
      *(ushort4*)(XWT2 + off) = u;
    }
}

// ---------------- gemm_ks8: P[kseg] = A[:, kseg] @ XW[kseg]  (bf16 partials) -------
// BM=128, BN=256, BK=32, ksplit=8. Grid 512 = 2 blocks/CU, 512 thr = 8 waves.
// Wave tile 128m x 32n (wave w owns n = w*32..w*32+31): NO wm-duplication of
// B-frag loads -> B-L2 1 MB/CU. A reg-staged f32->bf16 into frag-major linear
// LDS ([mi][fraglane][16B]): compute ds_read_b128 is lane-linear (free 2-way).
__global__ __launch_bounds__(512, 4) void gemm_ks8(
    const float* __restrict__ A,              // [8192][8192]
    const unsigned short* __restrict__ B2,    // XWT2 frag layout
    unsigned short* __restrict__ P) {         // [8][8192][256] bf16 partials
  __shared__ unsigned short Al[2][8 * 512];   // 2 x 8KB: [mi][fl][8bf16]

  const int bid = blockIdx.x;
  const int mtile = bid >> 3, kseg = bid & 7;  // kseg == XCD id (round-robin)
  const int m0 = mtile * 128;
  const int tid = threadIdx.x;  // 0..511
  const int w = tid >> 6, l = tid & 63;
  const int lr = l & 15, lq = l >> 4;

  // staging: thread t -> A row r=t>>2, k-chunk c4=t&3 (8 consecutive floats).
  // dest = frag (mi=r>>4), frag-lane fl=(r&15)+16*c4 -> exactly the MFMA A-frag.
  const int r = tid >> 2, c4 = tid & 3;
  const float* gA = A + (size_t)(m0 + r) * 8192 + kseg * 1024 + c4 * 8;
  const int woff = (r >> 4) * 512 + ((r & 15) + 16 * c4) * 8;  // ushort index

  const unsigned short* Bbase = B2 + (size_t)kseg * 262144 + l * 8;

  f32x4 acc[8][2];
#pragma unroll
  for (int i = 0; i < 8; ++i)
#pragma unroll
    for (int j = 0; j < 2; ++j) acc[i][j] = (f32x4){0.f, 0.f, 0.f, 0.f};

  f32x4 sa0, sa1;  // staged A regs
  bf16x8 Bf0, Bf1;

  auto loadA = [&](int h) {
    sa0 = *(const f32x4*)(gA + h * 32);
    sa1 = *(const f32x4*)(gA + h * 32 + 4);
  };
  auto writeA = [&](int h) {  // cvt + ds_write A(h) -> Al[h&1]
    bf16x8 b;
    b[0] = (__bf16)sa0.x; b[1] = (__bf16)sa0.y; b[2] = (__bf16)sa0.z; b[3] = (__bf16)sa0.w;
    b[4] = (__bf16)sa1.x; b[5] = (__bf16)sa1.y; b[6] = (__bf16)sa1.z; b[7] = (__bf16)sa1.w;
    *(bf16x8*)(&Al[h & 1][woff]) = b;
  };
  auto loadB = [&](int h) {  // iter h: k0=h*32 -> c=h>>1, kk=h&1; wave w = wp
    const unsigned short* p = Bbase + ((((h >> 1) * 8 + w) * 4 + (h & 1) * 2) << 9);
    Bf0 = *(const bf16x8*)(p);
    Bf1 = *(const bf16x8*)(p + 512);
  };
  auto compute = [&](int h) {
    const unsigned short* Ab = &Al[h & 1][0];
#pragma unroll
    for (int mi = 0; mi < 8; ++mi) {
      bf16x8 af = *(const bf16x8*)(Ab + mi * 512 + l * 8);  // lane-linear
      acc[mi][0] = __builtin_amdgcn_mfma_f32_16x16x32_bf16(af, Bf0, acc[mi][0], 0, 0, 0);
      acc[mi][1] = __builtin_amdgcn_mfma_f32_16x16x32_bf16(af, Bf1, acc[mi][1], 0, 0, 0);
    }
  };

  // prologue: A(0) staged+written, B(0)+A(1) in flight
  loadA(0);
  writeA(0);
  loadB(0);
  loadA(1);
  asm volatile("s_waitcnt lgkmcnt(0)" ::: "memory");
  asm volatile("s_barrier" ::: "memory");

  for (int h = 0; h < 31; ++h) {
    compute(h);          // compiler-counted vmcnt wait on Bf(h)
    loadB(h + 1);
    writeA(h + 1);       // compiler-counted vmcnt wait on sa(h+1)
    if (h < 30) loadA(h + 2);
    asm volatile("s_waitcnt lgkmcnt(0)" ::: "memory");
    asm volatile("s_barrier" ::: "memory");
  }
  compute(31);

  // epilogue: bf16 partial P[kseg][m][n]
  unsigned short* Pb = P + (size_t)kseg * (8192 * 256);
#pragma unroll
  for (int mi = 0; mi < 8; ++mi)
#pragma unroll
    for (int ni = 0; ni < 2; ++ni) {
      f32x4 z = acc[mi][ni];
      int n = w * 32 + ni * 16 + lr;
#pragma unroll
      for (int i = 0; i < 4; ++i) {
        int m = m0 + mi * 16 + lq * 4 + i;
        Pb[(size_t)m * 256 + n] = f2bf_bits(z[i]);
      }
    }
}

// ---------------- finalize8: out = x + s*(relu(sum P) - x) -------------------------
__global__ __launch_bounds__(256) void finalize8(
    const unsigned short* __restrict__ P,   // [8][8192][256] bf16
    const float* __restrict__ X,
    const float* __restrict__ s,
    float* __restrict__ out) {
  int i = blockIdx.x * 256 + threadIdx.x;  // 0..262143, 8 n-values each
  int m = i >> 5;
  float acc[8] = {0.f, 0.f, 0.f, 0.f, 0.f, 0.f, 0.f, 0.f};
#pragma unroll
  for (int ks = 0; ks < 8; ++ks) {
    u16x8 v = *(const u16x8*)(P + (size_t)ks * 2097152 + (size_t)i * 8);
#pragma unroll
    for (int j = 0; j < 8; ++j) acc[j] += bf2f(v[j]);
  }
  float sv = s[m];
  f32x4 x0 = *(const f32x4*)(X + (size_t)i * 8);
  f32x4 x1 = *(const f32x4*)(X + (size_t)i * 8 + 4);
  f32x4 o0, o1;
#pragma unroll
  for (int j = 0; j < 4; ++j) {
    o0[j] = x0[j] + sv * (fmaxf(acc[j], 0.f) - x0[j]);
    o1[j] = x1[j] + sv * (fmaxf(acc[4 + j], 0.f) - x1[j]);
  }
  *(f32x4*)(out + (size_t)i * 8) = o0;
  *(f32x4*)(out + (size_t)i * 8 + 4) = o1;
}

// ================= fallback path (round-6 kernels, unchanged) ======================
template <int NT, bool SPLIT>
__global__ __launch_bounds__(512, 4) void gemm_main(
    const float* __restrict__ A,
    const unsigned short* __restrict__ B2,
    const float* __restrict__ X,
    const float* __restrict__ s,
    float* __restrict__ out,
    float* __restrict__ P) {
  __shared__ float As[4][32 * 64];

  const int bid = blockIdx.x;
  const int m0 = SPLIT ? (bid >> 1) * 32 : bid * 32;
  const int khalf = SPLIT ? (bid & 1) : 0;
  const int tid = threadIdx.x;
  const int w = tid >> 6;
  const int l = tid & 63;
  const int lr = l & 15;
  const int lq = l >> 4;

  const int rA = tid >> 4;
  const int qA = tid & 15;
  const int sqA = qA ^ (rA & 15);
  const char* Asrc =
      (const char*)A + (size_t)(m0 + rA) * 32768 + (size_t)khalf * 16384 + sqA * 16;
  const char* Bbase =
      (const char*)B2 + (size_t)khalf * 64 * 32768 + (size_t)w * 4096 + (size_t)l * 16;

  f32x4 acc[2][2];
#pragma unroll
  for (int i = 0; i < 2; ++i)
#pragma unroll
    for (int j = 0; j < 2; ++j) acc[i][j] = (f32x4){0.f, 0.f, 0.f, 0.f};

  struct BF { bf16x8 a, b, c, d; };
  BF Bf0, Bf1;

  auto stageA = [&](int h, int buf) {
    gload16_stream(Asrc + (size_t)h * 256, (char*)&As[buf][0] + w * 1024);
  };
  auto loadB = [&](int h, BF& f) {
    const char* p = Bbase + (size_t)h * 32768;
    f.a = *(const bf16x8*)(p);
    f.b = *(const bf16x8*)(p + 1024);
    f.c = *(const bf16x8*)(p + 2048);
    f.d = *(const bf16x8*)(p + 3072);
  };

  auto compute = [&](int buf, const BF& f) {
    const char* Ab = (const char*)&As[buf][0];
    bf16x8 af[2][2];
#pragma unroll
    for (int kk = 0; kk < 2; ++kk)
#pragma unroll
      for (int mi = 0; mi < 2; ++mi) {
        int rr = mi * 16 + lr;
        int s0 = (kk * 8 + 2 * lq) ^ (rr & 15);
        int s1 = ((kk * 8 + 2 * lq) + 1) ^ (rr & 15);
        f32x4 a0 = *(const f32x4*)(Ab + rr * 256 + s0 * 16);
        f32x4 a1 = *(const f32x4*)(Ab + rr * 256 + s1 * 16);
        bf16x8 v;
        v[0] = (__bf16)a0.x; v[1] = (__bf16)a0.y; v[2] = (__bf16)a0.z; v[3] = (__bf16)a0.w;
        v[4] = (__bf16)a1.x; v[5] = (__bf16)a1.y; v[6] = (__bf16)a1.z; v[7] = (__bf16)a1.w;
        af[kk][mi] = v;
      }
    acc[0][0] = __builtin_amdgcn_mfma_f32_16x16x32_bf16(af[0][0], f.a, acc[0][0], 0, 0, 0);
    acc[0][1] = __builtin_amdgcn_mfma_f32_16x16x32_bf16(af[0][0], f.b, acc[0][1], 0, 0, 0);
    acc[1][0] = __builtin_amdgcn_mfma_f32_16x16x32_bf16(af[0][1], f.a, acc[1][0], 0, 0, 0);
    acc[1][1] = __builtin_amdgcn_mfma_f32_16x16x32_bf16(af[0][1], f.b, acc[1][1], 0, 0, 0);
    acc[0][0] = __builtin_amdgcn_mfma_f32_16x16x32_bf16(af[1][0], f.c, acc[0][0], 0, 0, 0);
    acc[0][1] = __builtin_amdgcn_mfma_f32_16x16x32_bf16(af[1][0], f.d, acc[0][1], 0, 0, 0);
    acc[1][0] = __builtin_amdgcn_mfma_f32_16x16x32_bf16(af[1][1], f.c, acc[1][0], 0, 0, 0);
    acc[1][1] = __builtin_amdgcn_mfma_f32_16x16x32_bf16(af[1][1], f.d, acc[1][1], 0, 0, 0);
  };

  stageA(0, 0);
  loadB(0, Bf0);
  stageA(1, 1);
  loadB(1, Bf1);
  stageA(2, 2);
  stageA(3, 3);

  for (int h = 0; h < NT - 4; h += 2) {
    asm volatile("s_waitcnt vmcnt(6)" ::: "memory");
    asm volatile("s_barrier" ::: "memory");
    compute(h & 3, Bf0);
    asm volatile("s_waitcnt lgkmcnt(0)" ::: "memory");
    asm volatile("s_barrier" ::: "memory");
    loadB(h + 2, Bf0);
    stageA(h + 4, h & 3);

    asm volatile("s_waitcnt vmcnt(6)" ::: "memory");
    asm volatile("s_barrier" ::: "memory");
    compute((h + 1) & 3, Bf1);
    asm volatile("s_waitcnt lgkmcnt(0)" ::: "memory");
    asm volatile("s_barrier" ::: "memory");
    loadB(h + 3, Bf1);
    stageA(h + 5, (h + 1) & 3);
  }
  asm volatile("s_waitcnt vmcnt(6)" ::: "memory");
  asm volatile("s_barrier" ::: "memory");
  compute(0, Bf0);
  asm volatile("s_waitcnt lgkmcnt(0)" ::: "memory");
  asm volatile("s_barrier" ::: "memory");
  loadB(NT - 2, Bf0);

  asm volatile("s_waitcnt vmcnt(5)" ::: "memory");
  asm volatile("s_barrier" ::: "memory");
  compute(1, Bf1);
  asm volatile("s_waitcnt lgkmcnt(0)" ::: "memory");
  asm volatile("s_barrier" ::: "memory");
  loadB(NT - 1, Bf1);

  asm volatile("s_waitcnt vmcnt(4)" ::: "memory");
  asm volatile("s_barrier" ::: "memory");
  compute(2, Bf0);
  asm volatile("s_waitcnt lgkmcnt(0)" ::: "memory");
  asm volatile("s_barrier" ::: "memory");

  asm volatile("s_waitcnt vmcnt(0)" ::: "memory");
  asm volatile("s_barrier" ::: "memory");
  compute(3, Bf1);

  if (SPLIT) {
    float* Pb = P + (size_t)khalf * 8192 * 256;
#pragma unroll
    for (int mi = 0; mi < 2; ++mi)
#pragma unroll
      for (int ni = 0; ni < 2; ++ni) {
        f32x4 z = acc[mi][ni];
        int n = w * 32 + ni * 16 + lr;
#pragma unroll
        for (int i = 0; i < 4; ++i) {
          int m = m0 + mi * 16 + lq * 4 + i;
          Pb[m * 256 + n] = z[i];
        }
      }
  } else {
#pragma unroll
    for (int mi = 0; mi < 2; ++mi)
#pragma unroll
      for (int ni = 0; ni < 2; ++ni) {
        f32x4 z = acc[mi][ni];
        int n = w * 32 + ni * 16 + lr;
#pragma unroll
        for (int i = 0; i < 4; ++i) {
          int m = m0 + mi * 16 + lq * 4 + i;
          float x = X[m * 256 + n];
          float sv = s[m];
          out[m * 256 + n] = x + sv * (fmaxf(z[i], 0.f) - x);
        }
      }
  }
}

__global__ __launch_bounds__(256) void finalize_kernel(
    const float* __restrict__ P,
    const float* __restrict__ X,
    const float* __restrict__ s,
    float* __restrict__ out) {
  int i = blockIdx.x * 256 + threadIdx.x;
  int m = i >> 6;
  f32x4 p0 = *(const f32x4*)(P + (size_t)i * 4);
  f32x4 p1 = *(const f32x4*)(P + 2097152 + (size_t)i * 4);
  f32x4 x = *(const f32x4*)(X + (size_t)i * 4);
  float sv = s[m];
  f32x4 o;
#pragma unroll
  for (int j = 0; j < 4; ++j) o[j] = x[j] + sv * (fmaxf(p0[j] + p1[j], 0.f) - x[j]);
  *(f32x4*)(out + (size_t)i * 4) = o;
}

extern "C" void kernel_launch(void* const* d_in, const int* in_sizes, int n_in,
                              void* d_out, int out_size, void* d_ws, size_t ws_size,
                              hipStream_t stream) {
  const float* X = (const float*)d_in[0];
  const float* A = (const float*)d_in[1];
  const float* wg = (const float*)d_in[2];
  const float* wl = (const float*)d_in[3];
  const float* W = (const float*)d_in[4];
  float* out = (float*)d_out;

  // ws: XWT2 4 MiB | WT 128 KiB | s 32 KiB | P (bf16 32 MiB new / f32 16 MiB old)
  unsigned short* XWT2 = (unsigned short*)d_ws;
  unsigned short* WT = (unsigned short*)((char*)d_ws + 4194304);
  float* s = (float*)((char*)d_ws + 4194304 + 131072);
  char* Pbase = (char*)d_ws + 4194304 + 131072 + 32768;

  prep_kernel<<<256, 256, 0, stream>>>(W, wg, wl, WT, s);
  gemm_xw<<<512, 256, 0, stream>>>(X, WT, XWT2);

  const size_t head = 4194304 + 131072 + 32768;
  const size_t need8 = head + (size_t)8 * 8192 * 256 * 2;   // bf16 partials
  const size_t need2 = head + (size_t)2 * 8192 * 256 * 4;   // f32 partials
  if (ws_size >= need8) {
    gemm_ks8<<<512, 512, 0, stream>>>(A, XWT2, (unsigned short*)Pbase);
    finalize8<<<1024, 256, 0, stream>>>((const unsigned short*)Pbase, X, s, out);
  } else if (ws_size >= need2) {
    gemm_main<64, true><<<512, 512, 0, stream>>>(A, XWT2, X, s, out, (float*)Pbase);
    finalize_kernel<<<2048, 256, 0, stream>>>((const float*)Pbase, X, s, out);
  } else {
    gemm_main<128, false><<<256, 512, 0, stream>>>(A, XWT2, X, s, out, nullptr);
  }
}